// Round 8
// baseline (376.620 us; speedup 1.0000x reference)
//
#include <hip/hip_runtime.h>
#include <stdint.h>

#define A_DIM 8192
#define B_DIM 8192
#define K_CL  256
#define BM    64
#define BK    64
#define NSLAB 4
#define SLABW (B_DIM / NSLAB)   // 2048
#define NKS   (SLABW / BK)      // 32
#define NPASS 4                 // DIAGNOSTIC: 4 identical passes so k_main shows in rocprof top-5

typedef short bf16x8 __attribute__((ext_vector_type(8)));
typedef float f32x4  __attribute__((ext_vector_type(4)));
typedef float f32x16 __attribute__((ext_vector_type(16)));
typedef unsigned short u16;

__device__ __forceinline__ u16 f2bf(float f) {
    unsigned int u = __float_as_uint(f);
    u += 0x7fffu + ((u >> 16) & 1u);   // RNE, finite inputs (prep only)
    return (u16)(u >> 16);
}

// ---------- prep: pack p_r into 32x32x16 MFMA B-fragment layout, bf16 ----------
__global__ __launch_bounds__(256) void k_prep(const float* __restrict__ pr,
                                              u16* __restrict__ Bpack,
                                              float* __restrict__ out) {
    const int kb2 = blockIdx.x;          // 0..511
    const int t = threadIdx.x;
    if (kb2 == 0 && t == 0) out[0] = 0.0f;
    const int lane = t & 63, wv = t >> 6;
    const int l31 = lane & 31, half = lane >> 5;
#pragma unroll
    for (int ci = 0; ci < 2; ci++) {
        const int c2 = wv * 2 + ci;
        float v[8];
#pragma unroll
        for (int j = 0; j < 8; j++)
            v[j] = pr[(size_t)(kb2 * 16 + half * 8 + j) * K_CL + c2 * 32 + l31];
        union { bf16x8 b; unsigned int u[4]; } o;
#pragma unroll
        for (int j = 0; j < 4; j++)
            o.u[j] = (unsigned int)f2bf(v[2 * j]) | ((unsigned int)f2bf(v[2 * j + 1]) << 16);
        *(bf16x8*)(Bpack + ((size_t)(kb2 * 8 + c2) * 64 + lane) * 8) = o.b;
    }
}

// ---------- main: r7 body, x NPASS for measurement ----------
__global__ __launch_bounds__(256, 2) void k_main(const float* __restrict__ w,
                                                 const float* __restrict__ pl,
                                                 const u16* __restrict__ Bpack,
                                                 const float* __restrict__ cp,
                                                 float* __restrict__ out,
                                                 float* __restrict__ dump) {
    __shared__ u16 Abf[2][BM * BK];      // 2 x 8 KB bf16, row = 128 B, XOR-swizzled
    __shared__ float rowsum[BM];
    __shared__ float red[4];

    const int bid = blockIdx.x;
    const int slab = bid & 3;
    const int m0 = (bid >> 2) * BM;
    const int tid = threadIdx.x;
    const int lane = tid & 63, wv = tid >> 6;
    const int l31 = lane & 31, half = lane >> 5;
    const int kb2base = slab * 128;

    const int g4  = lane >> 4;           // 0..3
    const int c16 = lane & 15;           // col chunk
    const float* wthr = w + (size_t)(m0 + wv * 16 + g4) * B_DIM + (size_t)slab * SLABW + c16 * 4;

    int wb[4];
#pragma unroll
    for (int i = 0; i < 4; i++) {
        const int row = wv * 16 + i * 4 + g4;
        wb[i] = row * 128 + ((c16 * 8) ^ ((row & 7) << 4));
    }

    float rcp_cp[2];
#pragma unroll
    for (int n2 = 0; n2 < 2; n2++)
        rcp_cp[n2] = 1.0f / cp[wv * 64 + n2 * 32 + l31];

#define GLOAD(R, ks) do {                                                                \
        const float* gp_ = wthr + (size_t)(ks) * BK;                                     \
        R##0 = *(const f32x4*)(gp_);                                                     \
        R##1 = *(const f32x4*)(gp_ + 4 * B_DIM);                                         \
        R##2 = *(const f32x4*)(gp_ + 8 * B_DIM);                                         \
        R##3 = *(const f32x4*)(gp_ + 12 * B_DIM);                                        \
    } while (0)

#define LOADB(arr, ks) do {                                                              \
        _Pragma("unroll")                                                                \
        for (int kf_ = 0; kf_ < 4; kf_++)                                                \
            _Pragma("unroll")                                                            \
            for (int n2_ = 0; n2_ < 2; n2_++)                                            \
                (arr)[kf_ * 2 + n2_] = *(const bf16x8*)(Bpack +                          \
                    (((size_t)(kb2base + (ks) * 4 + kf_) * 8 + wv * 2 + n2_) * 64 + lane) * 8); \
    } while (0)

#define PERM2(hi, lo) __builtin_amdgcn_perm(__float_as_uint(hi), __float_as_uint(lo), 0x07060302u)

#define CONVERT(R, buf) do {                                                             \
        sm0 += R##0[0] + R##0[1] + R##0[2] + R##0[3];                                    \
        sm1 += R##1[0] + R##1[1] + R##1[2] + R##1[3];                                    \
        sm2 += R##2[0] + R##2[1] + R##2[2] + R##2[3];                                    \
        sm3 += R##3[0] + R##3[1] + R##3[2] + R##3[3];                                    \
        uint2 p0_, p1_, p2_, p3_;                                                        \
        p0_.x = PERM2(R##0[1], R##0[0]); p0_.y = PERM2(R##0[3], R##0[2]);                \
        p1_.x = PERM2(R##1[1], R##1[0]); p1_.y = PERM2(R##1[3], R##1[2]);                \
        p2_.x = PERM2(R##2[1], R##2[0]); p2_.y = PERM2(R##2[3], R##2[2]);                \
        p3_.x = PERM2(R##3[1], R##3[0]); p3_.y = PERM2(R##3[3], R##3[2]);                \
        char* lb_ = (char*)&Abf[(buf)][0];                                               \
        *(uint2*)(lb_ + wb[0]) = p0_;                                                    \
        *(uint2*)(lb_ + wb[1]) = p1_;                                                    \
        *(uint2*)(lb_ + wb[2]) = p2_;                                                    \
        *(uint2*)(lb_ + wb[3]) = p3_;                                                    \
    } while (0)

#define COMPUTE(cur, arr) do {                                                           \
        const char* ab_ = (const char*)&Abf[(cur)][0];                                   \
        const int sx_ = (l31 & 7) << 4;                                                  \
        _Pragma("unroll")                                                                \
        for (int kf_ = 0; kf_ < 4; kf_++) {                                              \
            bf16x8 a0_ = *(const bf16x8*)(ab_ + (l31 * 128        + ((kf_ * 32 + half * 16) ^ sx_))); \
            bf16x8 a1_ = *(const bf16x8*)(ab_ + ((32 + l31) * 128 + ((kf_ * 32 + half * 16) ^ sx_))); \
            acc[0] = __builtin_amdgcn_mfma_f32_32x32x16_bf16(a0_, (arr)[kf_ * 2 + 0], acc[0], 0, 0, 0); \
            acc[1] = __builtin_amdgcn_mfma_f32_32x32x16_bf16(a0_, (arr)[kf_ * 2 + 1], acc[1], 0, 0, 0); \
            acc[2] = __builtin_amdgcn_mfma_f32_32x32x16_bf16(a1_, (arr)[kf_ * 2 + 0], acc[2], 0, 0, 0); \
            acc[3] = __builtin_amdgcn_mfma_f32_32x32x16_bf16(a1_, (arr)[kf_ * 2 + 1], acc[3], 0, 0, 0); \
        }                                                                                \
    } while (0)

#define BODYX(ks, WAITN, BC, BN, RC, RN, DOB, DOG, DOCONV, DOBAR) do {                   \
        if (DOB) LOADB(BN, (ks) + 1);                                                    \
        if (DOG) GLOAD(RN, (ks) + 2);                                                    \
        asm volatile("s_waitcnt vmcnt(" #WAITN ")" ::: "memory");                        \
        __builtin_amdgcn_sched_barrier(0);                                               \
        if (DOCONV) CONVERT(RC, ((ks) + 1) & 1);                                         \
        COMPUTE((ks) & 1, BC);                                                           \
        if (DOBAR) {                                                                     \
            asm volatile("s_waitcnt lgkmcnt(0)" ::: "memory");                           \
            __builtin_amdgcn_s_barrier();                                                \
            __builtin_amdgcn_sched_barrier(0);                                           \
        }                                                                                \
    } while (0)

    for (int pass = 0; pass < NPASS; ++pass) {
        float* dst = (pass == NPASS - 1) ? out : dump;

        f32x16 acc[4];   // [mf*2+n2]
#pragma unroll
        for (int i = 0; i < 4; i++)
#pragma unroll
            for (int r = 0; r < 16; r++) acc[i][r] = 0.f;
        float sm0 = 0.f, sm1 = 0.f, sm2 = 0.f, sm3 = 0.f;

        f32x4 rA0, rA1, rA2, rA3, rB0, rB1, rB2, rB3;
        bf16x8 bA[8], bB[8];

        // prologue: G0 -> rA, B0 -> bA, G1 -> rB; convert tile0
        GLOAD(rA, 0);
        LOADB(bA, 0);
        GLOAD(rB, 1);
        asm volatile("s_waitcnt vmcnt(12)" ::: "memory");   // rA (G0) arrived
        __builtin_amdgcn_sched_barrier(0);
        CONVERT(rA, 0);
        asm volatile("s_waitcnt lgkmcnt(0)" ::: "memory");
        __builtin_amdgcn_s_barrier();
        __builtin_amdgcn_sched_barrier(0);

        for (int ks = 0; ks < NKS - 2; ks += 2) {   // ks = 0..28
            BODYX(ks,     12, bA, bB, rB, rA, 1, 1, 1, 1);
            BODYX(ks + 1, 12, bB, bA, rA, rB, 1, 1, 1, 1);
        }
        BODYX(30, 8, bA, bB, rB, rA, 1, 0, 1, 1);   // loads B31; converts G31
        BODYX(31, 0, bB, bA, rA, rB, 0, 0, 0, 0);

        // row sums
        {
            float v0 = sm0, v1 = sm1, v2 = sm2, v3 = sm3;
#pragma unroll
            for (int o = 1; o <= 8; o <<= 1) {
                v0 += __shfl_xor(v0, o, 64);
                v1 += __shfl_xor(v1, o, 64);
                v2 += __shfl_xor(v2, o, 64);
                v3 += __shfl_xor(v3, o, 64);
            }
            if (c16 == 0) {
                rowsum[wv * 16 + 0 + g4]  = v0;
                rowsum[wv * 16 + 4 + g4]  = v1;
                rowsum[wv * 16 + 8 + g4]  = v2;
                rowsum[wv * 16 + 12 + g4] = v3;
            }
        }
        __syncthreads();

        // epilogue
        float tot = 0.f;
#pragma unroll
        for (int mf = 0; mf < 2; mf++) {
#pragma unroll
            for (int reg = 0; reg < 16; reg++) {
                const int lrow = mf * 32 + (reg & 3) + 8 * (reg >> 2) + 4 * half;
                const float rs = rowsum[lrow];
                const float* plrow = pl + (size_t)(m0 + lrow) * K_CL + wv * 64 + l31;
#pragma unroll
                for (int n2 = 0; n2 < 2; n2++) {
                    const float q = acc[mf * 2 + n2][reg];
                    const float p = plrow[n2 * 32];
                    tot += (q + p * (rs - 2.0f * q)) * rcp_cp[n2];
                }
            }
        }
        for (int o = 32; o; o >>= 1) tot += __shfl_down(tot, o, 64);
        if (lane == 0) red[wv] = tot;
        __syncthreads();
        if (tid == 0) atomicAdd(dst, red[0] + red[1] + red[2] + red[3]);
        __syncthreads();   // rowsum/red reused next pass
    }

#undef BODYX
#undef COMPUTE
#undef CONVERT
#undef PERM2
#undef LOADB
#undef GLOAD
}

extern "C" void kernel_launch(void* const* d_in, const int* in_sizes, int n_in,
                              void* d_out, int out_size, void* d_ws, size_t ws_size,
                              hipStream_t stream) {
    const float* w  = (const float*)d_in[0];
    const float* pl = (const float*)d_in[1];
    const float* pr = (const float*)d_in[2];
    const float* cp = (const float*)d_in[3];
    float* out = (float*)d_out;

    u16* Bpack = (u16*)d_ws;                                          // 4 MB
    float* dump = (float*)((char*)d_ws + (size_t)4 * 1024 * 1024);    // diagnostic sink

    k_prep<<<dim3(512), dim3(256), 0, stream>>>(pr, Bpack, out);
    k_main<<<dim3(128 * NSLAB), dim3(256), 0, stream>>>(w, pl, Bpack, cp, out, dump);
}

// Round 9
// 68.216 us; speedup vs baseline: 5.5210x; 5.5210x over previous
//
#include <hip/hip_runtime.h>
#include <stdint.h>

#define A_DIM 8192
#define B_DIM 8192
#define K_CL  256
#define NSLAB 8
#define SLABW (B_DIM / NSLAB)   // 1024
#define NKS   (SLABW / 64)      // 16 K-steps of 64

typedef short bf16x8 __attribute__((ext_vector_type(8)));
typedef float f32x4  __attribute__((ext_vector_type(4)));
typedef float f32x16 __attribute__((ext_vector_type(16)));
typedef unsigned short u16;

__device__ __forceinline__ u16 f2bf(float f) {
    unsigned int u = __float_as_uint(f);
    u += 0x7fffu + ((u >> 16) & 1u);   // RNE (prep only)
    return (u16)(u >> 16);
}

// ---------- prep: pack p_r into 32x32x16 MFMA B-fragment layout, bf16 ----------
// Bpack[((kb2*8 + c2)*64 + lane)*8 + j] = bf16(p_r[kb2*16 + (lane>>5)*8 + j][c2*32 + (lane&31)])
__global__ __launch_bounds__(256) void k_prep(const float* __restrict__ pr,
                                              u16* __restrict__ Bpack,
                                              float* __restrict__ out) {
    const int kb2 = blockIdx.x;          // 0..511
    const int t = threadIdx.x;
    if (kb2 == 0 && t == 0) out[0] = 0.0f;
    const int lane = t & 63, wv = t >> 6;
    const int l31 = lane & 31, half = lane >> 5;
#pragma unroll
    for (int ci = 0; ci < 2; ci++) {
        const int c2 = wv * 2 + ci;
        float v[8];
#pragma unroll
        for (int j = 0; j < 8; j++)
            v[j] = pr[(size_t)(kb2 * 16 + half * 8 + j) * K_CL + c2 * 32 + l31];
        union { bf16x8 b; unsigned int u[4]; } o;
#pragma unroll
        for (int j = 0; j < 4; j++)
            o.u[j] = (unsigned int)f2bf(v[2 * j]) | ((unsigned int)f2bf(v[2 * j + 1]) << 16);
        *(bf16x8*)(Bpack + ((size_t)(kb2 * 8 + c2) * 64 + lane) * 8) = o.b;
    }
}

// ---------- main: barrier-free self-paced waves, wave-private LDS transpose ----------
__global__ __launch_bounds__(256, 2) void k_main(const float* __restrict__ w,
                                                 const float* __restrict__ pl,
                                                 const u16* __restrict__ Bpack,
                                                 const float* __restrict__ cp,
                                                 float* __restrict__ out) {
    __shared__ u16 Abf[4][2][2048];      // per-wave private double buffer (4 KB each)
    __shared__ float rowsum_s[4][32];
    __shared__ float red[4];

    const int bid = blockIdx.x;
    const int slab = bid & 7;            // == XCD on round-robin dispatch -> Bpack slice L2-resident
    const int mt  = bid >> 3;
    const int tid = threadIdx.x;
    const int lane = tid & 63, wv = tid >> 6;
    const int l31 = lane & 31, half = lane >> 5;
    const int g4 = lane >> 4, c16 = lane & 15;

    const int m0w = mt * 128 + wv * 32;          // this wave's 32-row strip
    const size_t kbase = (size_t)slab * SLABW;
    const int kb2base = slab * 64;

    const float* wthr = w + (size_t)(m0w + g4) * B_DIM + kbase + c16 * 4;
    u16* lds = &Abf[wv][0][0];
    const int swz = (l31 & 7) << 4;

    f32x16 acc[8];
#pragma unroll
    for (int i = 0; i < 8; i++)
#pragma unroll
        for (int r = 0; r < 16; r++) acc[i][r] = 0.f;
    float sm[8] = {0.f, 0.f, 0.f, 0.f, 0.f, 0.f, 0.f, 0.f};

    f32x4 G[8];
    bf16x8 Bc[8], Bn[8];

#define WAIT8 do { asm volatile("s_waitcnt vmcnt(8)" ::: "memory"); __builtin_amdgcn_sched_barrier(0); } while (0)
#define WAIT0 do { asm volatile("s_waitcnt vmcnt(0)" ::: "memory"); __builtin_amdgcn_sched_barrier(0); } while (0)
#define LGKM0 do { asm volatile("s_waitcnt lgkmcnt(0)" ::: "memory"); __builtin_amdgcn_sched_barrier(0); } while (0)

#define GLOAD(ks) do {                                                                   \
        _Pragma("unroll")                                                                \
        for (int j_ = 0; j_ < 8; j_++)                                                   \
            G[j_] = *(const f32x4*)(wthr + (size_t)(4 * j_) * B_DIM + (size_t)(ks) * 64);\
    } while (0)

#define LOADB(arr, s_, kf_) do {                                                         \
        const u16* bp_ = Bpack + (size_t)(kb2base + (s_) * 4 + (kf_)) * 512 + lane * 8;  \
        _Pragma("unroll")                                                                \
        for (int n2_ = 0; n2_ < 8; n2_++)                                                \
            (arr)[n2_] = *(const bf16x8*)(bp_ + n2_ * 512);                              \
    } while (0)

#define PERM2(hi, lo) __builtin_amdgcn_perm(__float_as_uint(hi), __float_as_uint(lo), 0x07060302u)

#define CONVERT(bufsel) do {                                                             \
        char* lb_ = (char*)lds + (bufsel) * 4096;                                        \
        _Pragma("unroll")                                                                \
        for (int j_ = 0; j_ < 8; j_++) {                                                 \
            sm[j_] += G[j_][0] + G[j_][1] + G[j_][2] + G[j_][3];                         \
            uint2 pj_;                                                                   \
            pj_.x = PERM2(G[j_][1], G[j_][0]);                                           \
            pj_.y = PERM2(G[j_][3], G[j_][2]);                                           \
            *(uint2*)(lb_ + (512 * j_ + 128 * g4)                                        \
                          + ((c16 * 8) ^ (g4 << 4) ^ ((j_ & 1) << 6))) = pj_;            \
        }                                                                                \
    } while (0)

#define KFSTEP(kf_, bufsel, Barr) do {                                                   \
        bf16x8 a_ = *(const bf16x8*)((const char*)lds + (bufsel) * 4096 + l31 * 128      \
                                     + (((kf_) * 32 + half * 16) ^ swz));                \
        __builtin_amdgcn_s_setprio(1);                                                   \
        _Pragma("unroll")                                                                \
        for (int n2_ = 0; n2_ < 8; n2_++)                                                \
            acc[n2_] = __builtin_amdgcn_mfma_f32_32x32x16_bf16(a_, (Barr)[n2_],          \
                                                               acc[n2_], 0, 0, 0);       \
        __builtin_amdgcn_s_setprio(0);                                                   \
    } while (0)

    // prologue: stage tile 0, start G(1) and B(0,0)
    GLOAD(0);
    WAIT0;
    CONVERT(0);
    GLOAD(1);              // queue: [G1:8]
    LOADB(Bc, 0, 0);       // queue: [G1:8][B00:8]
    LGKM0;

    for (int s = 0; s < NKS - 1; ++s) {      // s = 0..14
        const int buf = s & 1;
        LOADB(Bn, s, 1);      WAIT8; KFSTEP(0, buf, Bc);
        LOADB(Bc, s, 2);      WAIT8; KFSTEP(1, buf, Bn);
        LOADB(Bn, s, 3);      WAIT8; KFSTEP(2, buf, Bc);
        LOADB(Bc, s + 1, 0);  WAIT8; KFSTEP(3, buf, Bn);
        CONVERT(buf ^ 1);                    // G(s+1) was drained at kf0's WAIT8
        if (s < NKS - 2) GLOAD(s + 2);
        LGKM0;
    }
    // final step s = 15, buf = 1, no prefetch beyond slab
    LOADB(Bn, 15, 1); WAIT8; KFSTEP(0, 1, Bc);
    LOADB(Bc, 15, 2); WAIT8; KFSTEP(1, 1, Bn);
    LOADB(Bn, 15, 3); WAIT8; KFSTEP(2, 1, Bc);
    WAIT0;                   KFSTEP(3, 1, Bn);

#undef KFSTEP
#undef CONVERT
#undef PERM2
#undef LOADB
#undef GLOAD

    // per-wave row sums: sm[j] holds cols c16*4..+3 of row 4j+g4; reduce over c16
    {
#pragma unroll
        for (int j = 0; j < 8; j++) {
            float v = sm[j];
            v += __shfl_xor(v, 1, 64);
            v += __shfl_xor(v, 2, 64);
            v += __shfl_xor(v, 4, 64);
            v += __shfl_xor(v, 8, 64);
            if (c16 == 0) rowsum_s[wv][4 * j + g4] = v;
        }
    }
    // same wave wrote it; compiler orders the LDS dependence
    float rcp_cp[8];
#pragma unroll
    for (int n2 = 0; n2 < 8; n2++)
        rcp_cp[n2] = 1.0f / cp[n2 * 32 + l31];

    // epilogue: tot = sum over (row,col) of [q*(1-2p) + rowW_slab*p] / cp
    // C/D 32x32: col = lane&31, row = (reg&3) + 8*(reg>>2) + 4*(lane>>5)
    float tot = 0.f;
#pragma unroll
    for (int reg = 0; reg < 16; reg++) {
        const int lrow = (reg & 3) + 8 * (reg >> 2) + 4 * half;
        const float rs = rowsum_s[wv][lrow];
        const float* plrow = pl + (size_t)(m0w + lrow) * K_CL + l31;
#pragma unroll
        for (int n2 = 0; n2 < 8; n2++) {
            const float q = acc[n2][reg];
            const float p = plrow[n2 * 32];
            tot += (q + p * (rs - 2.0f * q)) * rcp_cp[n2];
        }
    }
    for (int o = 32; o; o >>= 1) tot += __shfl_down(tot, o, 64);
    if (lane == 0) red[wv] = tot;
    __syncthreads();
    if (tid == 0) atomicAdd(out, red[0] + red[1] + red[2] + red[3]);

#undef WAIT8
#undef WAIT0
#undef LGKM0
}

extern "C" void kernel_launch(void* const* d_in, const int* in_sizes, int n_in,
                              void* d_out, int out_size, void* d_ws, size_t ws_size,
                              hipStream_t stream) {
    const float* w  = (const float*)d_in[0];
    const float* pl = (const float*)d_in[1];
    const float* pr = (const float*)d_in[2];
    const float* cp = (const float*)d_in[3];
    float* out = (float*)d_out;

    u16* Bpack = (u16*)d_ws;   // 4 MB

    k_prep<<<dim3(512), dim3(256), 0, stream>>>(pr, Bpack, out);
    k_main<<<dim3(64 * NSLAB), dim3(256), 0, stream>>>(w, pl, Bpack, cp, out);
}